// Round 1
// baseline (84.309 us; speedup 1.0000x reference)
//
#include <hip/hip_runtime.h>

typedef __bf16 bf16x8 __attribute__((ext_vector_type(8)));
typedef float f32x4 __attribute__((ext_vector_type(4)));

#define E 64            // head dim
#define BUCKET 256
#define WIN 512
#define KB 32           // keys per chunk
#define NCHUNK 16
#define QW 32           // queries per wave
#define KSTR 72         // sK row stride (elements) -> 144B, 16B aligned, 2-way banks
#define VSTR 40         // sV row stride (elements) -> 80B, 16B aligned, 2-way banks
#define PSTR 40         // sP row stride

__global__ __launch_bounds__(512)
void local_attn_kernel(const float* __restrict__ qg,
                       const float* __restrict__ kg,
                       const float* __restrict__ vg,
                       float* __restrict__ og)
{
    __shared__ __align__(16) __bf16 sK[KB][KSTR];       // [key][dim]
    __shared__ __align__(16) __bf16 sV[E][VSTR];        // [dim][key]  (transposed)
    __shared__ __align__(16) __bf16 sP[8][2][16][PSTR]; // per-wave, per-Mtile P scratch

    const int blk  = blockIdx.x;      // 0..511
    const int bh   = blk >> 4;        // batch-head 0..31
    const int bi   = blk & 15;        // bucket 0..15
    const int tid  = threadIdx.x;
    const int w    = tid >> 6;        // wave 0..7
    const int lane = tid & 63;
    const int lo   = lane & 15;
    const int hi   = lane >> 4;       // 0..3

    const long long base = (long long)bh * (4096LL * 64LL);
    const float* qb = qg + base + (long long)(bi * BUCKET) * E;
    const float* kb = kg + base + ((long long)(bi - 1) * BUCKET) * E; // window start
    const float* vb = vg + base + ((long long)(bi - 1) * BUCKET) * E;
    float*       ob = og + base + (long long)(bi * BUCKET) * E;

    // ---- preload Q A-frags: qa[mt][kk]; lane holds row (w*32+mt*16+lo), k = kk*32+8*hi+i
    bf16x8 qa[2][2];
#pragma unroll
    for (int mt = 0; mt < 2; ++mt)
#pragma unroll
      for (int kk = 0; kk < 2; ++kk) {
        const float* src = qb + (w * QW + mt * 16 + lo) * E + kk * 32 + 8 * hi;
        float4 f0 = *(const float4*)(src);
        float4 f1 = *(const float4*)(src + 4);
        bf16x8 t;
        t[0] = (__bf16)f0.x; t[1] = (__bf16)f0.y; t[2] = (__bf16)f0.z; t[3] = (__bf16)f0.w;
        t[4] = (__bf16)f1.x; t[5] = (__bf16)f1.y; t[6] = (__bf16)f1.z; t[7] = (__bf16)f1.w;
        qa[mt][kk] = t;
      }

    f32x4 o[2][4];
#pragma unroll
    for (int mt = 0; mt < 2; ++mt)
#pragma unroll
      for (int nt = 0; nt < 4; ++nt)
        o[mt][nt] = f32x4{0.f, 0.f, 0.f, 0.f};
    float mrow[2][4], lrow[2][4];
#pragma unroll
    for (int mt = 0; mt < 2; ++mt)
#pragma unroll
      for (int r = 0; r < 4; ++r) { mrow[mt][r] = -3.0e38f; lrow[mt][r] = 0.0f; }

    const int c0 = (bi == 0) ? 8 : 0;   // bucket 0: first 256 window keys are pad
    for (int c = c0; c < NCHUNK; ++c) {
        // ---- stage chunk c (keys [32c,32c+32)) : K row-major, V transposed ----
        {
            const int key = tid >> 4;          // 0..31
            const int d0  = (tid & 15) * 4;    // 0..60
            const float4 kf = *(const float4*)(kb + (long long)(c * KB + key) * E + d0);
            const float4 vf = *(const float4*)(vb + (long long)(c * KB + key) * E + d0);
            sK[key][d0 + 0] = (__bf16)kf.x;
            sK[key][d0 + 1] = (__bf16)kf.y;
            sK[key][d0 + 2] = (__bf16)kf.z;
            sK[key][d0 + 3] = (__bf16)kf.w;
            sV[d0 + 0][key] = (__bf16)vf.x;
            sV[d0 + 1][key] = (__bf16)vf.y;
            sV[d0 + 2][key] = (__bf16)vf.z;
            sV[d0 + 3][key] = (__bf16)vf.w;
        }
        __syncthreads();

        if (c <= w + 8) {  // wave-uniform causal chunk skip
            // B-frags for QK^T: lane holds key col (nt*16+lo), k = kk*32+8*hi+i
            bf16x8 kbf[2][2];
#pragma unroll
            for (int nt = 0; nt < 2; ++nt)
#pragma unroll
              for (int kk = 0; kk < 2; ++kk)
                kbf[nt][kk] = *(const bf16x8*)&sK[nt * 16 + lo][kk * 32 + 8 * hi];

            f32x4 s[2][2];
#pragma unroll
            for (int mt = 0; mt < 2; ++mt)
#pragma unroll
              for (int nt = 0; nt < 2; ++nt) {
                f32x4 acc = f32x4{0.f, 0.f, 0.f, 0.f};
                acc = __builtin_amdgcn_mfma_f32_16x16x32_bf16(qa[mt][0], kbf[nt][0], acc, 0, 0, 0);
                acc = __builtin_amdgcn_mfma_f32_16x16x32_bf16(qa[mt][1], kbf[nt][1], acc, 0, 0, 0);
                s[mt][nt] = acc;
              }

#pragma unroll
            for (int mt = 0; mt < 2; ++mt) {
                float p[2][4];
#pragma unroll
                for (int r = 0; r < 4; ++r) {
                    const int qrow = w * QW + mt * 16 + hi * 4 + r;  // query local in bucket
#pragma unroll
                    for (int nt = 0; nt < 2; ++nt) {
                        const int j = c * KB + nt * 16 + lo;          // key local in window
                        float val = s[mt][nt][r] * 0.125f;            // e^-0.5 = 1/8
                        if (j > qrow + 256) val = -3.0e38f;           // causal mask
                        p[nt][r] = val;
                    }
                }
#pragma unroll
                for (int r = 0; r < 4; ++r) {
                    float cmax = fmaxf(p[0][r], p[1][r]);
#pragma unroll
                    for (int d = 1; d < 16; d <<= 1)
                        cmax = fmaxf(cmax, __shfl_xor(cmax, d, 64));
                    const float mnew  = fmaxf(mrow[mt][r], cmax);
                    const float alpha = __expf(mrow[mt][r] - mnew);
                    const float p0 = __expf(p[0][r] - mnew);
                    const float p1 = __expf(p[1][r] - mnew);
                    p[0][r] = p0; p[1][r] = p1;
                    float rs = p0 + p1;
#pragma unroll
                    for (int d = 1; d < 16; d <<= 1)
                        rs += __shfl_xor(rs, d, 64);
                    lrow[mt][r] = lrow[mt][r] * alpha + rs;
                    mrow[mt][r] = mnew;
#pragma unroll
                    for (int nt = 0; nt < 4; ++nt) o[mt][nt][r] *= alpha;
                }
                // P (C-layout) -> scratch -> A-layout
#pragma unroll
                for (int nt = 0; nt < 2; ++nt)
#pragma unroll
                  for (int r = 0; r < 4; ++r)
                    sP[w][mt][hi * 4 + r][nt * 16 + lo] = (__bf16)p[nt][r];
            }

            // PV: B-frags from transposed V; A-frags from scratch
            bf16x8 vbf[4];
#pragma unroll
            for (int nt = 0; nt < 4; ++nt)
                vbf[nt] = *(const bf16x8*)&sV[nt * 16 + lo][8 * hi];
#pragma unroll
            for (int mt = 0; mt < 2; ++mt) {
                bf16x8 pa = *(const bf16x8*)&sP[w][mt][lo][8 * hi];
#pragma unroll
                for (int nt = 0; nt < 4; ++nt)
                    o[mt][nt] = __builtin_amdgcn_mfma_f32_16x16x32_bf16(pa, vbf[nt], o[mt][nt], 0, 0, 0);
            }
        }
        __syncthreads();
    }

    // ---- epilogue: normalize and store ----
#pragma unroll
    for (int mt = 0; mt < 2; ++mt)
#pragma unroll
      for (int nt = 0; nt < 4; ++nt)
#pragma unroll
        for (int r = 0; r < 4; ++r) {
            const int qrow = w * QW + mt * 16 + hi * 4 + r;
            ob[(long long)qrow * E + nt * 16 + lo] = o[mt][nt][r] / lrow[mt][r];
        }
}

extern "C" void kernel_launch(void* const* d_in, const int* in_sizes, int n_in,
                              void* d_out, int out_size, void* d_ws, size_t ws_size,
                              hipStream_t stream) {
    const float* q = (const float*)d_in[0];
    const float* k = (const float*)d_in[1];
    const float* v = (const float*)d_in[2];
    float* out = (float*)d_out;
    // 32 batch-heads * 16 buckets = 512 blocks, 512 threads (8 waves) each
    local_attn_kernel<<<dim3(512), dim3(512), 0, stream>>>(q, k, v, out);
}

// Round 3
// 40.359 us; speedup vs baseline: 2.0890x; 2.0890x over previous
//
#include <hip/hip_runtime.h>

typedef __bf16 bf16x8 __attribute__((ext_vector_type(8)));
typedef float f32x4 __attribute__((ext_vector_type(4)));
typedef unsigned int u32;
typedef unsigned short u16;

#define KB 64      // keys per chunk
#define NCH 8      // chunks per 512-key window
#define KSTR 72    // sK row stride (elems) = 144B (16B-aligned rows, 4-bank rotation)
#define PSP 72     // sP row stride (elems) = 144B
#define VPS 68     // sVp row stride (dwords), mult of 4 for b128 stores

static __device__ __forceinline__ u32 pack_bf2(float a, float b) {
    u16 x = __builtin_bit_cast(u16, (__bf16)a);
    u16 y = __builtin_bit_cast(u16, (__bf16)b);
    return (u32)x | ((u32)y << 16);
}

__global__ __launch_bounds__(512)
void local_attn_kernel(const float* __restrict__ qg, const float* __restrict__ kg,
                       const float* __restrict__ vg, float* __restrict__ og)
{
    __shared__ __align__(16) __bf16 sK[KB][KSTR];          // [key][dim]
    __shared__ __align__(16) u32    sVp[32][VPS];          // [keypair][dim] (2 keys packed)
    __shared__ __align__(16) __bf16 sP[8][2][16][PSP];     // per-wave P scratch, XOR-swizzled

    // XCD-aware swizzle (bijective bit-rotation): neighbors sharing K/V land on one XCD
    const int bid = ((blockIdx.x & 7) << 6) | (blockIdx.x >> 3);
    const int bh = bid >> 4, bi = bid & 15;
    const int tid = threadIdx.x, w = tid >> 6;
    const int lane = tid & 63, lo = lane & 15, hi = lane >> 4;

    const long long base = (long long)bh << 18;            // *4096*64
    const float* qb = qg + base + ((long long)bi << 14);   // *256*64
    const float* kb = kg + base + (((long long)(bi - 1)) << 14);
    const float* vb = vg + base + (((long long)(bi - 1)) << 14);
    float*       ob = og + base + ((long long)bi << 14);

    // ---- Q A-frags (pre-scaled by 1/8): lane holds row (w*32+mt*16+lo), k = kk*32+8*hi+i
    bf16x8 qa[2][2];
#pragma unroll
    for (int mt = 0; mt < 2; ++mt)
#pragma unroll
      for (int kk = 0; kk < 2; ++kk) {
        const float* src = qb + (w * 32 + mt * 16 + lo) * 64 + kk * 32 + 8 * hi;
        float4 f0 = *(const float4*)(src);
        float4 f1 = *(const float4*)(src + 4);
        bf16x8 t;
        t[0] = (__bf16)(f0.x * 0.125f); t[1] = (__bf16)(f0.y * 0.125f);
        t[2] = (__bf16)(f0.z * 0.125f); t[3] = (__bf16)(f0.w * 0.125f);
        t[4] = (__bf16)(f1.x * 0.125f); t[5] = (__bf16)(f1.y * 0.125f);
        t[6] = (__bf16)(f1.z * 0.125f); t[7] = (__bf16)(f1.w * 0.125f);
        qa[mt][kk] = t;
      }

    f32x4 o[2][4];
#pragma unroll
    for (int mt = 0; mt < 2; ++mt)
#pragma unroll
      for (int nt = 0; nt < 4; ++nt)
        o[mt][nt] = f32x4{0.f, 0.f, 0.f, 0.f};
    float lsum[2][4];
#pragma unroll
    for (int mt = 0; mt < 2; ++mt)
#pragma unroll
      for (int r = 0; r < 4; ++r) lsum[mt][r] = 0.0f;

    // staging thread mapping
    const int skey = tid >> 3;          // 0..63  (K: one key, 8 dims)
    const int sd0  = (tid & 7) * 8;
    const int vkp  = tid >> 4;          // 0..31  (V: key-pair, 4 dims)
    const int vd0  = (tid & 15) * 4;
    const float* kA = kb + (long long)skey * 64 + sd0;
    const float* vA = vb + (long long)(2 * vkp) * 64 + vd0;

    const int c0 = (bi == 0) ? 4 : 0;   // bucket 0: first 256 window keys are pad

    for (int c = c0; c < NCH; ++c) {
        // ---- stage chunk c: global -> convert -> LDS (no cross-iteration state) ----
        {
            const float* p = kA + c * (KB * 64);
            float4 kf0 = *(const float4*)p;
            float4 kf1 = *(const float4*)(p + 4);
            const float* q2 = vA + c * (KB * 64);
            float4 vf0 = *(const float4*)q2;
            float4 vf1 = *(const float4*)(q2 + 64);
            bf16x8 kv;
            kv[0] = (__bf16)kf0.x; kv[1] = (__bf16)kf0.y; kv[2] = (__bf16)kf0.z; kv[3] = (__bf16)kf0.w;
            kv[4] = (__bf16)kf1.x; kv[5] = (__bf16)kf1.y; kv[6] = (__bf16)kf1.z; kv[7] = (__bf16)kf1.w;
            *(bf16x8*)&sK[skey][sd0] = kv;
            uint4 pk;
            pk.x = pack_bf2(vf0.x, vf1.x); pk.y = pack_bf2(vf0.y, vf1.y);
            pk.z = pack_bf2(vf0.z, vf1.z); pk.w = pack_bf2(vf0.w, vf1.w);
            *((uint4*)&sVp[vkp][vd0]) = pk;
        }
        __syncthreads();

        if ((c << 6) <= 32 * w + 287) {   // wave-uniform causal chunk skip
            // ---- QK^T ----
            f32x4 s[2][4];
#pragma unroll
            for (int nt = 0; nt < 4; ++nt) {
                bf16x8 kb0 = *(const bf16x8*)&sK[nt * 16 + lo][8 * hi];
                bf16x8 kb1 = *(const bf16x8*)&sK[nt * 16 + lo][32 + 8 * hi];
                f32x4 z = f32x4{0.f, 0.f, 0.f, 0.f};
                s[0][nt] = __builtin_amdgcn_mfma_f32_16x16x32_bf16(qa[0][0], kb0, z, 0, 0, 0);
                s[0][nt] = __builtin_amdgcn_mfma_f32_16x16x32_bf16(qa[0][1], kb1, s[0][nt], 0, 0, 0);
                s[1][nt] = __builtin_amdgcn_mfma_f32_16x16x32_bf16(qa[1][0], kb0, z, 0, 0, 0);
                s[1][nt] = __builtin_amdgcn_mfma_f32_16x16x32_bf16(qa[1][1], kb1, s[1][nt], 0, 0, 0);
            }

            // ---- exp (scores bounded, no max subtraction), mask, lsum, P->LDS ----
#pragma unroll
            for (int mt = 0; mt < 2; ++mt)
#pragma unroll
              for (int nt = 0; nt < 4; ++nt) {
                const int j = (c << 6) + nt * 16 + lo;   // key pos in window
#pragma unroll
                for (int r = 0; r < 4; ++r) {
                    const int qrow = w * 32 + mt * 16 + hi * 4 + r;
                    const float p = (j > qrow + 256) ? 0.f : __expf(s[mt][nt][r]);
                    lsum[mt][r] += p;
                    const int row = hi * 4 + r;
                    sP[w][mt][row][(nt * 16 + lo) ^ ((row & 8) << 1)] = (__bf16)p;
                }
              }

            // ---- PV ----
#pragma unroll
            for (int kk = 0; kk < 2; ++kk) {
                bf16x8 vbf[4];
#pragma unroll
                for (int nt = 0; nt < 4; ++nt) {
                    union { u32 d[4]; bf16x8 v; } uv;
#pragma unroll
                    for (int j = 0; j < 4; ++j)
                        uv.d[j] = sVp[kk * 16 + 4 * hi + j][nt * 16 + lo];
                    vbf[nt] = uv.v;
                }
#pragma unroll
                for (int mt = 0; mt < 2; ++mt) {
                    bf16x8 pa = *(const bf16x8*)&sP[w][mt][lo][(kk * 32 + 8 * hi) ^ ((lo & 8) << 1)];
#pragma unroll
                    for (int nt = 0; nt < 4; ++nt)
                        o[mt][nt] = __builtin_amdgcn_mfma_f32_16x16x32_bf16(pa, vbf[nt], o[mt][nt], 0, 0, 0);
                }
            }
        }
        __syncthreads();
    }

    // ---- epilogue: one row-sum reduce, normalize, store ----
#pragma unroll
    for (int mt = 0; mt < 2; ++mt)
#pragma unroll
      for (int r = 0; r < 4; ++r) {
        float l = lsum[mt][r];
        l += __shfl_xor(l, 1, 64);
        l += __shfl_xor(l, 2, 64);
        l += __shfl_xor(l, 4, 64);
        l += __shfl_xor(l, 8, 64);
        const float inv = 1.0f / l;
        const int qrow = w * 32 + mt * 16 + hi * 4 + r;
        float* orow = ob + (long long)qrow * 64;
#pragma unroll
        for (int nt = 0; nt < 4; ++nt)
            orow[nt * 16 + lo] = o[mt][nt][r] * inv;
      }
}

extern "C" void kernel_launch(void* const* d_in, const int* in_sizes, int n_in,
                              void* d_out, int out_size, void* d_ws, size_t ws_size,
                              hipStream_t stream) {
    const float* q = (const float*)d_in[0];
    const float* k = (const float*)d_in[1];
    const float* v = (const float*)d_in[2];
    float* out = (float*)d_out;
    local_attn_kernel<<<dim3(512), dim3(512), 0, stream>>>(q, k, v, out);
}

// Round 5
// 35.913 us; speedup vs baseline: 2.3476x; 1.1238x over previous
//
#include <hip/hip_runtime.h>

typedef __bf16 bf16x8 __attribute__((ext_vector_type(8)));
typedef float f32x16 __attribute__((ext_vector_type(16)));
typedef int i32x2 __attribute__((ext_vector_type(2)));
typedef unsigned int u32;

#define NCH 8   // 8 chunks of 64 keys = 512-key window

static __device__ __forceinline__ u32 cvt_pk_bf16(float lo, float hi) {
    u32 r;
    asm("v_cvt_pk_bf16_f32 %0, %1, %2" : "=v"(r) : "v"(lo), "v"(hi));
    return r;
}

__global__ __launch_bounds__(512, 4)
void local_attn_kernel(const float* __restrict__ qg, const float* __restrict__ kg,
                       const float* __restrict__ vg, float* __restrict__ og)
{
    // K: [buf][key][dim], 16B-slot XOR-swizzled (slot ^= key&7) -> conflict-free b128 reads
    __shared__ __align__(16) __bf16 sK[2][64][64];
    // V: [buf][dim][keypair] u32 (keys 2k,2k+1 packed), slot-swizzled -> b128 frag reads
    __shared__ __align__(16) u32 sVp[2][64][32];

    const int bid = ((blockIdx.x & 7) << 6) | (blockIdx.x >> 3);  // XCD swizzle (bijective)
    const int bh = bid >> 4, bi = bid & 15;
    const int tid = threadIdx.x, w = tid >> 6;
    const int lane = tid & 63, l31 = lane & 31, h = lane >> 5;

    const long long base = (long long)bh << 18;           // *4096*64
    const float* qp = qg + base + ((long long)bi << 14);  // *256*64
    const float* kp = kg + base + (((long long)(bi - 1)) << 14);
    const float* vp = vg + base + (((long long)(bi - 1)) << 14);
    float*       op = og + base + ((long long)bi << 14);

    // ---- Q B-frags, pre-scaled by 0.125*log2(e); lane: query=w*32+l31, dim=ks*16+8h+i
    bf16x8 qf[4];
    {
        const float QS = 0.18033688011112042f;   // (1/8)*log2(e): exp(s/8)=2^(s*QS)
        const float* qrow = qp + (w * 32 + l31) * 64 + 8 * h;
#pragma unroll
        for (int ks = 0; ks < 4; ++ks) {
            float4 f0 = *(const float4*)(qrow + ks * 16);
            float4 f1 = *(const float4*)(qrow + ks * 16 + 4);
            bf16x8 t;
            t[0] = (__bf16)(f0.x * QS); t[1] = (__bf16)(f0.y * QS);
            t[2] = (__bf16)(f0.z * QS); t[3] = (__bf16)(f0.w * QS);
            t[4] = (__bf16)(f1.x * QS); t[5] = (__bf16)(f1.y * QS);
            t[6] = (__bf16)(f1.z * QS); t[7] = (__bf16)(f1.w * QS);
            qf[ks] = t;
        }
    }

    f32x16 o0, o1;
#pragma unroll
    for (int i = 0; i < 16; ++i) { o0[i] = 0.f; o1[i] = 0.f; }
    float lsum = 0.f;

    // staging maps (coalesced global)
    const int skey = tid >> 3, stg = tid & 7;              // K: key, 16B dim-group
    const int kslot = (stg ^ (skey & 7)) << 3;             // swizzled element offset
    const int vkp = tid >> 4, vd0 = (tid & 15) * 4;        // V: keypair, 4 dims
    const float* kA = kp + skey * 64 + stg * 8;
    const float* vA = vp + (2 * vkp) * 64 + vd0;

    const int c0 = (bi == 0) ? 4 : 0;      // bucket 0: first 256 window keys are pad
    const int qpos = w * 32 + l31;         // query position within bucket
    const int wlim = 32 * w + 287;         // chunk/kt active threshold

    int cur = 0;

    auto stage = [&](int c, int buf) {
        const float* ks_ = kA + c * (64 * 64);
        float4 k0 = *(const float4*)ks_;
        float4 k1 = *(const float4*)(ks_ + 4);
        const float* vs_ = vA + c * (64 * 64);
        float4 v0 = *(const float4*)vs_;
        float4 v1 = *(const float4*)(vs_ + 64);
        bf16x8 kv;
        kv[0] = (__bf16)k0.x; kv[1] = (__bf16)k0.y; kv[2] = (__bf16)k0.z; kv[3] = (__bf16)k0.w;
        kv[4] = (__bf16)k1.x; kv[5] = (__bf16)k1.y; kv[6] = (__bf16)k1.z; kv[7] = (__bf16)k1.w;
        *(bf16x8*)&sK[buf][skey][kslot] = kv;
        u32 p0 = cvt_pk_bf16(v0.x, v1.x);
        u32 p1 = cvt_pk_bf16(v0.y, v1.y);
        u32 p2 = cvt_pk_bf16(v0.z, v1.z);
        u32 p3 = cvt_pk_bf16(v0.w, v1.w);
        const int kq = vkp >> 2, kj = vkp & 3;
        sVp[buf][vd0 + 0][((kq ^ ((vd0 + 0) & 7)) << 2) + kj] = p0;
        sVp[buf][vd0 + 1][((kq ^ ((vd0 + 1) & 7)) << 2) + kj] = p1;
        sVp[buf][vd0 + 2][((kq ^ ((vd0 + 2) & 7)) << 2) + kj] = p2;
        sVp[buf][vd0 + 3][((kq ^ ((vd0 + 3) & 7)) << 2) + kj] = p3;
    };

    stage(c0, 0);

    for (int c = c0; c < NCH; ++c) {
        __syncthreads();                       // one barrier per chunk (double-buffered)
        if (c + 1 < NCH) stage(c + 1, cur ^ 1);

        const int kbase = c * 64;
#pragma unroll
        for (int kt = 0; kt < 2; ++kt) {
            if (kbase + 32 * kt > wlim) continue;   // wave-uniform causal skip

            // ---- QK^T swapped: S[key][query] = mfma(K_A, Q_B) ----
            const int key = kt * 32 + l31;
            const int ksw = key & 7;
            bf16x8 kfa[4];
#pragma unroll
            for (int ks = 0; ks < 4; ++ks)
                kfa[ks] = *(const bf16x8*)&sK[cur][key][((ks * 2 + h) ^ ksw) << 3];
            f32x16 s;
#pragma unroll
            for (int i = 0; i < 16; ++i) s[i] = 0.f;
#pragma unroll
            for (int ks = 0; ks < 4; ++ks)
                s = __builtin_amdgcn_mfma_f32_32x32x16_bf16(kfa[ks], qf[ks], s, 0, 0, 0);

            // ---- exp2 (scores bounded; no max-tracking), mask only on boundary kt ----
            float pv[16];
            const int jb = kbase + 32 * kt + 4 * h;     // + reg-offset = key pos
            if (kbase + 32 * kt + 31 <= 32 * w + 256) { // fully unmasked for this wave
#pragma unroll
                for (int r = 0; r < 16; ++r) {
                    pv[r] = __builtin_amdgcn_exp2f(s[r]);
                    lsum += pv[r];
                }
            } else {
#pragma unroll
                for (int r = 0; r < 16; ++r) {
                    const int j = jb + (r & 3) + 8 * (r >> 2);
                    float e = __builtin_amdgcn_exp2f(s[r]);
                    pv[r] = (j > qpos + 256) ? 0.f : e;
                    lsum += pv[r];
                }
            }

            // ---- P -> bf16 A-frags in-register (cvt_pk + permlane32_swap) ----
            // lane holds keys 4h+{0,1,2,3}, 8+4h+{..}, 16+4h+{..}, 24+4h+{..} (r-major)
            // A-frag needs keys kis*16+8h+0..7 as 4 u32 words.
            u32 wds[8];
#pragma unroll
            for (int m = 0; m < 8; ++m)
                wds[m] = cvt_pk_bf16(pv[2 * m], pv[2 * m + 1]);

#pragma unroll
            for (int kis = 0; kis < 2; ++kis) {
                // permlane32_swap(vdst, vsrc): vdst.hi31 <-> vsrc.lo31;
                // returns (new_vdst, new_vsrc) = (word_lo, word_hi)
                i32x2 r02 = __builtin_amdgcn_permlane32_swap(
                    (int)wds[4 * kis + 0], (int)wds[4 * kis + 2], false, false);
                i32x2 r13 = __builtin_amdgcn_permlane32_swap(
                    (int)wds[4 * kis + 1], (int)wds[4 * kis + 3], false, false);
                union { u32 u[4]; bf16x8 b; } pu;
                pu.u[0] = (u32)r02.x; pu.u[1] = (u32)r13.x;
                pu.u[2] = (u32)r02.y; pu.u[3] = (u32)r13.y;

                const int slot = ((kt * 2 + kis) * 2 + h) ^ (l31 & 7);
                bf16x8 vb0 = *(const bf16x8*)&sVp[cur][l31][slot << 2];
                bf16x8 vb1 = *(const bf16x8*)&sVp[cur][32 + l31][slot << 2];
                o0 = __builtin_amdgcn_mfma_f32_32x32x16_bf16(pu.b, vb0, o0, 0, 0, 0);
                o1 = __builtin_amdgcn_mfma_f32_32x32x16_bf16(pu.b, vb1, o1, 0, 0, 0);
            }
        }
        cur ^= 1;
    }

    // ---- epilogue: combine half-sums, broadcast per-query inv, normalize, store ----
    lsum += __shfl_xor(lsum, 32, 64);
    const float inv = 1.0f / lsum;     // valid at lane l31 for query w*32+l31
#pragma unroll
    for (int r = 0; r < 16; ++r) {
        const int qr = (r & 3) + 8 * (r >> 2) + 4 * h;   // query row of C reg r
        const float iq = __shfl(inv, qr, 64);
        float* orow = op + (w * 32 + qr) * 64;
        orow[l31]      = o0[r] * iq;
        orow[32 + l31] = o1[r] * iq;
    }
}

extern "C" void kernel_launch(void* const* d_in, const int* in_sizes, int n_in,
                              void* d_out, int out_size, void* d_ws, size_t ws_size,
                              hipStream_t stream) {
    const float* q = (const float*)d_in[0];
    const float* k = (const float*)d_in[1];
    const float* v = (const float*)d_in[2];
    float* out = (float*)d_out;
    local_attn_kernel<<<dim3(512), dim3(512), 0, stream>>>(q, k, v, out);
}